// Round 11
// baseline (62.500 us; speedup 1.0000x reference)
//
#include <hip/hip_runtime.h>
#include <stdint.h>

#define Bdim 512
#define Tdim 2000
#define Ddim 20
#define Hdim 128
#define Cdim 10
#define TT   64
#define NCH  32              // 31 full chunks + 16-step tail
#define BETA 0.95f
#define THR  0.8f

typedef float f32x2 __attribute__((ext_vector_type(2)));
typedef float f32x4 __attribute__((ext_vector_type(4)));
typedef int   i32x4 __attribute__((ext_vector_type(4)));

// f32 pair -> packed bf16 hi + packed bf16 lo (RNE)
#define CVT_HILO(HI, LO, F0, F1) {                                                     \
    asm volatile("v_cvt_pk_bf16_f32 %0, %1, %2" : "=v"(HI) : "v"(F0), "v"(F1));        \
    const float h0f_ = __uint_as_float((HI) << 16);                                    \
    const float h1f_ = __uint_as_float((HI) & 0xFFFF0000u);                            \
    const float l0_ = (F0) - h0f_;  const float l1_ = (F1) - h1f_;                     \
    asm volatile("v_cvt_pk_bf16_f32 %0, %1, %2" : "=v"(LO) : "v"(l0_), "v"(l1_)); }

#define MFMA0(ACC, A8, B8) \
  asm volatile("v_mfma_f32_16x16x32_bf16 %0, %1, %2, 0"  : "=v"(ACC) : "v"(A8), "v"(B8));
#define MFMA(ACC, A8, B8)  \
  asm volatile("v_mfma_f32_16x16x32_bf16 %0, %1, %2, %0" : "+v"(ACC) : "v"(A8), "v"(B8));

__global__ __launch_bounds__(256, 1) void snn_spec2_kernel(
    const float* __restrict__ x,   // [B,T,D]
    const float* __restrict__ W1,  // [H,D]
    const float* __restrict__ b1,  // [H]
    const float* __restrict__ W2,  // [C,H]
    const float* __restrict__ b2,  // [C]
    float* __restrict__ out)       // [B,C]
{
  const int b   = blockIdx.x;
  const int tid = threadIdx.x;    // 0..255
  const int wid = tid >> 6;       // 0,1: producers; 2,3: scanners
  const int l   = tid & 63;
  const int r   = l & 15;
  const int g   = l >> 4;

  __shared__ __align__(16) float xraw[2][TT * Ddim];    // 10240 B (rows of 20 f32)
  __shared__ __align__(16) float cur[2][TT * 132];      // 67584 B, t-major stride 132
  __shared__ float cnt_s[Hdim];

  const float* xb = x + (size_t)b * (Tdim * Ddim);
  const float* const clampMax = x + (size_t)Bdim * Tdim * Ddim - 4;

  const uint32_t xrawB = (uint32_t)(uintptr_t)&xraw[0][0];
  const uint32_t curB  = (uint32_t)(uintptr_t)&cur[0][0];

  // ---------------- producer-only setup ----------------
  i32x4 bhi[8], blo[8];
  f32x4 zero4, ovr;
  bool  sel23 = false, g3f = false;
  if (wid < 2) {
    const bool g2 = (g == 2);
    g3f   = (g == 3);
    sel23 = g2 | g3f;
    zero4[0]=0.f; zero4[1]=0.f; zero4[2]=0.f; zero4[3]=0.f;
    ovr = zero4; if (g2) ovr[0] = 1.0f;    // A column k=20 := 1.0 (bias rider)
#pragma unroll
    for (int ni = 0; ni < 8; ++ni) {
      const int hh = ni * 16 + r;
      float wv[8];
#pragma unroll
      for (int j = 0; j < 8; ++j) {
        const int k = 8 * g + j;
        wv[j] = (k < Ddim) ? W1[hh * Ddim + k] : ((k == Ddim) ? b1[hh] : 0.0f);
      }
#pragma unroll
      for (int d = 0; d < 4; ++d) {
        const uint32_t u0 = __float_as_uint(wv[2*d]), u1 = __float_as_uint(wv[2*d+1]);
        const uint32_t h0 = (u0 + 0x8000u) & 0xFFFF0000u;
        const uint32_t h1 = (u1 + 0x8000u) & 0xFFFF0000u;
        bhi[ni][d] = (int)(h1 | (h0 >> 16));
        const float l0 = wv[2*d]   - __uint_as_float(h0);
        const float l1 = wv[2*d+1] - __uint_as_float(h1);
        const uint32_t e0 = (__float_as_uint(l0) + 0x8000u) & 0xFFFF0000u;
        const uint32_t e1 = (__float_as_uint(l1) + 0x8000u) & 0xFFFF0000u;
        blo[ni][d] = (int)(e1 | (e0 >> 16));
      }
    }
  }

  // ---------------- scanner-only state ----------------
  float    mem = 0.0f;
  bool     sp  = false;
  uint32_t cnt = 0u;
  f32x2    negT2; negT2[0] = -THR; negT2[1] = -THR;
  const int sid = wid - 2;

  // Each producer wave stages ITS OWN 32 t-rows (2560 B) -> no cross-wave xraw dep.
#define STAGE(CH, BUF) do {                                                            \
    const float* g0_ = xb + (CH) * 1280 + wid * 640 + l * 4;                           \
    char* lb_ = (char*)&xraw[0][0] + (BUF) * 5120 + wid * 2560 + l * 16;               \
    const float* p0_ = g0_;        if (p0_ > clampMax) p0_ = clampMax;                 \
    const float* p1_ = g0_ + 256;  if (p1_ > clampMax) p1_ = clampMax;                 \
    __builtin_amdgcn_global_load_lds(                                                  \
      (const __attribute__((address_space(1))) unsigned int*)p0_,                      \
      (__attribute__((address_space(3))) unsigned int*)lb_, 16, 0, 0);                 \
    __builtin_amdgcn_global_load_lds(                                                  \
      (const __attribute__((address_space(1))) unsigned int*)p1_,                      \
      (__attribute__((address_space(3))) unsigned int*)(lb_ + 1024), 16, 0, 0);        \
    if (l < 32) {                                                                      \
      const float* p2_ = g0_ + 512;  if (p2_ > clampMax) p2_ = clampMax;               \
      __builtin_amdgcn_global_load_lds(                                                \
        (const __attribute__((address_space(1))) unsigned int*)p2_,                    \
        (__attribute__((address_space(3))) unsigned int*)(lb_ + 2048), 16, 0, 0);      \
    } } while (0)

#define CW2(NI, AC)                                                                    \
    asm volatile("ds_write2_b32 %0, %1, %2 offset0:%c3 offset1:%c4"                    \
                 :: "v"(cwb_),  "v"(AC[0]), "v"(AC[1]), "n"(16*(NI)), "n"(16*(NI)+132)); \
    asm volatile("ds_write2_b32 %0, %1, %2 offset0:%c3 offset1:%c4"                    \
                 :: "v"(cwb2_), "v"(AC[2]), "v"(AC[3]), "n"(16*(NI)), "n"(16*(NI)+132));

#define CWRM(MTIDX, P0,P1,P2,P3,P4,P5,P6,P7) {                                         \
    const uint32_t cwb_  = curB + (uint32_t)(pbuf * 33792 + 528 * ((MTIDX) * 16 + 4 * g) + 4 * r); \
    const uint32_t cwb2_ = cwb_ + 1056u;                                               \
    CW2(0,P0) CW2(1,P1) CW2(2,P2) CW2(3,P3) CW2(4,P4) CW2(5,P5) CW2(6,P6) CW2(7,P7) }

#define SELA(A0, A1) { A0 = g3f ? zero4 : A0;  A1 = sel23 ? ovr : A1; }

#define CVT8(AHI, ALO, A0, A1) {                                                       \
    uint32_t h_, lo_;                                                                  \
    CVT_HILO(h_, lo_, A0[0], A0[1]) AHI[0]=(int)h_; ALO[0]=(int)lo_;                   \
    CVT_HILO(h_, lo_, A0[2], A0[3]) AHI[1]=(int)h_; ALO[1]=(int)lo_;                   \
    CVT_HILO(h_, lo_, A1[0], A1[1]) AHI[2]=(int)h_; ALO[2]=(int)lo_;                   \
    CVT_HILO(h_, lo_, A1[2], A1[3]) AHI[3]=(int)h_; ALO[3]=(int)lo_; }

#define MM24(AHI, ALO, C0,C1,C2,C3,C4,C5,C6,C7)                                        \
    MFMA0(C0, ALO, bhi[0]) MFMA0(C1, ALO, bhi[1]) MFMA0(C2, ALO, bhi[2])               \
    MFMA0(C3, ALO, bhi[3]) MFMA0(C4, ALO, bhi[4]) MFMA0(C5, ALO, bhi[5])               \
    MFMA0(C6, ALO, bhi[6]) MFMA0(C7, ALO, bhi[7])                                      \
    MFMA (C0, AHI, blo[0]) MFMA (C1, AHI, blo[1]) MFMA (C2, AHI, blo[2])               \
    MFMA (C3, AHI, blo[3]) MFMA (C4, AHI, blo[4]) MFMA (C5, AHI, blo[5])               \
    MFMA (C6, AHI, blo[6]) MFMA (C7, AHI, blo[7])                                      \
    MFMA (C0, AHI, bhi[0]) MFMA (C1, AHI, bhi[1]) MFMA (C2, AHI, bhi[2])               \
    MFMA (C3, AHI, bhi[3]) MFMA (C4, AHI, bhi[4]) MFMA (C5, AHI, bhi[5])               \
    MFMA (C6, AHI, bhi[6]) MFMA (C7, AHI, bhi[7])

  // Both 16-t tiles fused: 4 A-reads upfront, counted waits, all C-writes at end.
#define GEMM2() {                                                                      \
    const uint32_t afb_ = xrawB + (uint32_t)(pbuf * 5120 + (2*wid) * 1280 + 80 * r + 32 * g); \
    f32x4 a00_, a01_, a10_, a11_;                                                      \
    asm volatile("ds_read_b128 %0, %1 offset:0"    : "=v"(a00_) : "v"(afb_));          \
    asm volatile("ds_read_b128 %0, %1 offset:16"   : "=v"(a01_) : "v"(afb_));          \
    asm volatile("ds_read_b128 %0, %1 offset:1280" : "=v"(a10_) : "v"(afb_));          \
    asm volatile("ds_read_b128 %0, %1 offset:1296" : "=v"(a11_) : "v"(afb_));          \
    asm volatile("s_waitcnt lgkmcnt(2)" ::: "memory");                                 \
    __builtin_amdgcn_sched_barrier(0);                                                 \
    SELA(a00_, a01_)                                                                   \
    i32x4 ahi0_, alo0_;  CVT8(ahi0_, alo0_, a00_, a01_)                                \
    asm volatile("s_nop 2");                                                           \
    f32x4 c00,c01,c02,c03,c04,c05,c06,c07;                                             \
    MM24(ahi0_, alo0_, c00,c01,c02,c03,c04,c05,c06,c07)                                \
    asm volatile("s_waitcnt lgkmcnt(0)" ::: "memory");                                 \
    __builtin_amdgcn_sched_barrier(0);                                                 \
    SELA(a10_, a11_)                                                                   \
    i32x4 ahi1_, alo1_;  CVT8(ahi1_, alo1_, a10_, a11_)                                \
    asm volatile("s_nop 2");                                                           \
    f32x4 c10,c11,c12,c13,c14,c15,c16,c17;                                             \
    MM24(ahi1_, alo1_, c10,c11,c12,c13,c14,c15,c16,c17)                                \
    asm volatile("s_nop 7"); asm volatile("s_nop 4");                                  \
    CWRM(2*wid,     c00,c01,c02,c03,c04,c05,c06,c07)                                   \
    CWRM(2*wid + 1, c10,c11,c12,c13,c14,c15,c16,c17) }

#define GEMM_TAIL() {                                                                  \
    const uint32_t afb_ = xrawB + (uint32_t)(pbuf * 5120 + 80 * r + 32 * g);           \
    f32x4 a00_, a01_;                                                                  \
    asm volatile("ds_read_b128 %0, %1 offset:0"  : "=v"(a00_) : "v"(afb_));            \
    asm volatile("ds_read_b128 %0, %1 offset:16" : "=v"(a01_) : "v"(afb_));            \
    asm volatile("s_waitcnt lgkmcnt(0)" ::: "memory");                                 \
    __builtin_amdgcn_sched_barrier(0);                                                 \
    SELA(a00_, a01_)                                                                   \
    i32x4 ahi0_, alo0_;  CVT8(ahi0_, alo0_, a00_, a01_)                                \
    asm volatile("s_nop 2");                                                           \
    f32x4 c00,c01,c02,c03,c04,c05,c06,c07;                                             \
    MM24(ahi0_, alo0_, c00,c01,c02,c03,c04,c05,c06,c07)                                \
    asm volatile("s_nop 7"); asm volatile("s_nop 4");                                  \
    CWRM(0, c00,c01,c02,c03,c04,c05,c06,c07) }

  // ---- scanner machinery: dual-fma 8-cyc chain, depth-8 read2 ring ----
#define RD2(PR, AD) asm volatile("ds_read2_b32 %0, %1 offset0:0 offset1:132" : "=v"(PR) : "v"(AD));
#define LGW(N) asm volatile("s_waitcnt lgkmcnt(" #N ")" ::: "memory"); __builtin_amdgcn_sched_barrier(0);
#define CONSUME(PR) {                                                                  \
    f32x2 cm_; asm("v_pk_add_f32 %0, %1, %2" : "=v"(cm_) : "v"(PR), "v"(negT2));       \
    float mP_ = fmaf(BETA, mem, PR[0]);                                                \
    float mM_ = fmaf(BETA, mem, cm_[0]);                                               \
    mem = sp ? mM_ : mP_;                                                              \
    sp  = mem > THR;                                                                   \
    cnt += sp ? 1u : 0u;                                                               \
    mP_ = fmaf(BETA, mem, PR[1]);                                                      \
    mM_ = fmaf(BETA, mem, cm_[1]);                                                     \
    mem = sp ? mM_ : mP_;                                                              \
    sp  = mem > THR;                                                                   \
    cnt += sp ? 1u : 0u; }
#define SSLOT(S) { LGW(7) CONSUME(pr##S) a##S += 8448u; RD2(pr##S, a##S) }
#define TSLOT(S, W) { LGW(W) CONSUME(pr##S) }
#define SCAN_PRO()                                                                     \
    uint32_t a0 = spB, a1 = spB+1056u, a2 = spB+2112u, a3 = spB+3168u,                 \
             a4 = spB+4224u, a5 = spB+5280u, a6 = spB+6336u, a7 = spB+7392u;           \
    f32x2 pr0, pr1, pr2, pr3, pr4, pr5, pr6, pr7;                                      \
    RD2(pr0,a0) RD2(pr1,a1) RD2(pr2,a2) RD2(pr3,a3)                                    \
    RD2(pr4,a4) RD2(pr5,a5) RD2(pr6,a6) RD2(pr7,a7)
#define SCAN_TAIL8()                                                                   \
    TSLOT(0,7) TSLOT(1,6) TSLOT(2,5) TSLOT(3,4)                                        \
    TSLOT(4,3) TSLOT(5,2) TSLOT(6,1) TSLOT(7,0)

  // ================= main phase loop =================
  if (wid < 2) STAGE(0, 0);

#pragma unroll 1
  for (int ph = 0; ph <= NCH; ++ph) {
    if (wid < 2) {
      // ------- producer: GEMM chunk ph (own-staged), stage chunk ph+1 -------
      if (ph <= NCH - 1) {
        asm volatile("s_waitcnt vmcnt(0)" ::: "memory");   // own staging for chunk ph
        if (ph < NCH - 1) STAGE(ph + 1, (ph + 1) & 1);
        const int pbuf = ph & 1;
        if (ph < NCH - 1) {
          GEMM2()
        } else if (wid == 0) {     // tail: 16 steps
          GEMM_TAIL()
        }
        asm volatile("s_waitcnt lgkmcnt(0)" ::: "memory"); // cur writes retired
      }
    } else {
      // ------- scanner: scan chunk ph-1 -------
      if (ph >= 1) {
        const uint32_t spB = curB + (uint32_t)(((ph - 1) & 1) * 33792 + 4 * (sid * 64 + l));
        if (ph - 1 < NCH - 1) {
          SCAN_PRO()
          SSLOT(0) SSLOT(1) SSLOT(2) SSLOT(3) SSLOT(4) SSLOT(5) SSLOT(6) SSLOT(7)
          SSLOT(0) SSLOT(1) SSLOT(2) SSLOT(3) SSLOT(4) SSLOT(5) SSLOT(6) SSLOT(7)
          SSLOT(0) SSLOT(1) SSLOT(2) SSLOT(3) SSLOT(4) SSLOT(5) SSLOT(6) SSLOT(7)
          SCAN_TAIL8()
        } else {                   // tail chunk: 16 steps
          SCAN_PRO()
          SCAN_TAIL8()
        }
        if (ph == NCH) cnt_s[sid * 64 + l] = (float)cnt;
      }
    }
    // raw barrier: producers drained lgkm above; scanners have no pending DS;
    // outstanding global_load_lds (next chunk, wave-private) intentionally
    // stays in flight across the barrier.
    __builtin_amdgcn_sched_barrier(0);
    __builtin_amdgcn_s_barrier();
    __builtin_amdgcn_sched_barrier(0);
  }

  __syncthreads();   // full drain once (cnt_s visible)

  // ---- fused epilogue: logits from spike counts ----
  if (tid < Cdim) {
    float dot = 0.0f;
#pragma unroll
    for (int k = 0; k < Hdim; ++k)
      dot = fmaf(cnt_s[k], W2[tid * Hdim + k], dot);
    const float Tf = (float)Tdim;
    const float scale = 1.0f / Tf + 0.1f / (Tf + 1e-6f);
    out[b * Cdim + tid] = fmaf(dot, scale, 1.1f * b2[tid]);
  }
}

extern "C" void kernel_launch(void* const* d_in, const int* in_sizes, int n_in,
                              void* d_out, int out_size, void* d_ws, size_t ws_size,
                              hipStream_t stream) {
  const float* x  = (const float*)d_in[0];
  const float* W1 = (const float*)d_in[1];
  const float* b1 = (const float*)d_in[2];
  const float* W2 = (const float*)d_in[3];
  const float* b2 = (const float*)d_in[4];
  float* out = (float*)d_out;

  snn_spec2_kernel<<<dim3(Bdim), dim3(256), 0, stream>>>(x, W1, b1, W2, b2, out);
}